// Round 2
// 147.277 us; speedup vs baseline: 1.2758x; 1.2758x over previous
//
#include <hip/hip_runtime.h>
#include <hip/hip_bf16.h>
#include <math.h>

#define VOCAB 50257
#define VPAD  50304   // 393*128
#define DMODEL 128
#define BATCH 4096
#define NW 10         // 2*WINDOW
#define LOG2E 1.4426950408889634f

typedef __bf16 bf16_t;
typedef __bf16 bf16x4 __attribute__((ext_vector_type(4)));
typedef __bf16 bf16x8 __attribute__((ext_vector_type(8)));
typedef float  floatx4 __attribute__((ext_vector_type(4)));

#if __has_builtin(__builtin_amdgcn_exp2f)
#define EXP2(x) __builtin_amdgcn_exp2f(x)
#else
#define EXP2(x) exp2f(x)
#endif

typedef const __attribute__((address_space(1))) void* gvp;
typedef __attribute__((address_space(3))) void* svp;

// ---------------------------------------------------------------------------
// Kernel 1 (merged prep) — unchanged from baseline:
//  blocks [0,512):   cbow = mean of 10 ctx embeddings -> bf16 (pre-scaled by
//                    log2e), center logit in fp32, sumexp zero-init.
//  blocks [512,3656): W fp32 -> bf16 padded to VPAD rows.
// ---------------------------------------------------------------------------
#define PREP_CBOW_BLOCKS 512
#define PREP_WCONV_BLOCKS 3144   // VPAD*128 / (256*8)

__global__ void k_prep(const int* __restrict__ ctx, const int* __restrict__ center,
                       const float* __restrict__ emb, const float* __restrict__ W,
                       bf16_t* __restrict__ cbow_bf, bf16_t* __restrict__ Wb,
                       float* __restrict__ center_logit, float* __restrict__ sumexp) {
    const int tid = threadIdx.x;
    if (blockIdx.x < PREP_CBOW_BLOCKS) {
        const int g32 = tid >> 5;       // 0..7
        const int l32 = tid & 31;
        const int b = blockIdx.x * 8 + g32;
        const int* cr = ctx + b * NW;
        float4 s = make_float4(0.f, 0.f, 0.f, 0.f);
#pragma unroll
        for (int w = 0; w < NW; ++w) {
            const int id = cr[w];
            float4 v = *reinterpret_cast<const float4*>(emb + (long)id * DMODEL + l32 * 4);
            s.x += v.x; s.y += v.y; s.z += v.z; s.w += v.w;
        }
        s.x *= 0.1f; s.y *= 0.1f; s.z *= 0.1f; s.w *= 0.1f;
        bf16x4 o;
        o[0] = (bf16_t)(s.x * LOG2E); o[1] = (bf16_t)(s.y * LOG2E);
        o[2] = (bf16_t)(s.z * LOG2E); o[3] = (bf16_t)(s.w * LOG2E);
        *reinterpret_cast<bf16x4*>(cbow_bf + b * DMODEL + l32 * 4) = o;

        const int cid = center[b];
        float4 wv = *reinterpret_cast<const float4*>(W + (long)cid * DMODEL + l32 * 4);
        float p = s.x * wv.x + s.y * wv.y + s.z * wv.z + s.w * wv.w;
#pragma unroll
        for (int off = 16; off >= 1; off >>= 1) p += __shfl_xor(p, off, 64);
        if (l32 == 0) {
            center_logit[b] = p;
            sumexp[b] = 0.f;
        }
    } else {
        const long base = ((long)(blockIdx.x - PREP_CBOW_BLOCKS) * 256 + tid) * 8;
        bf16x8 o;
        if (base < (long)VOCAB * DMODEL) {
            float4 a = *reinterpret_cast<const float4*>(W + base);
            float4 b = *reinterpret_cast<const float4*>(W + base + 4);
            o[0] = (bf16_t)a.x; o[1] = (bf16_t)a.y; o[2] = (bf16_t)a.z; o[3] = (bf16_t)a.w;
            o[4] = (bf16_t)b.x; o[5] = (bf16_t)b.y; o[6] = (bf16_t)b.z; o[7] = (bf16_t)b.w;
        } else {
            o = (bf16x8)(bf16_t)0.f;
        }
        *reinterpret_cast<bf16x8*>(Wb + base) = o;
    }
}

// ---------------------------------------------------------------------------
// Kernel 2: persistent fused logits GEMM + 2^x + per-row sumexp.
//   Grid 16 x 32 = 512 blocks (exactly 2/CU). Each block loops over n-tiles
//   nt = by, by+32, ... (12-13 tiles), with double-buffered B staging:
//     STAGE(next) -> COMPUTE(cur) -> s_waitcnt vmcnt(0); s_barrier
//   so next-tile loads fly under the current tile's MFMAs (no __syncthreads
//   vmcnt(0)-drain before compute). A fragments loaded ONCE per block.
//   Per-thread sumexp accumulated across tiles; shuffles+atomics once at end.
// ---------------------------------------------------------------------------
#define BM 256
#define BN 128
#define NTILES 393    // VPAD/BN
#define NSPLIT 32

__device__ __forceinline__ void stage_tile(const bf16_t* __restrict__ Wb,
                                           bf16_t* bs, int n0, int wv, int l15, int q) {
    // Fragment-order staging: region f = nf*4+ks holds lane L's 16B at
    // bs + f*1024B + L*16B (linear dest, as global_load_lds requires).
#pragma unroll
    for (int i = 0; i < 8; ++i) {
        const int f = wv * 8 + i;
        const int nf = f >> 2, ks = f & 3;
        const bf16_t* g = Wb + (long)(n0 + nf * 16 + l15) * DMODEL + ks * 32 + q * 8;
        __builtin_amdgcn_global_load_lds((gvp)g, (svp)(bs + f * 512), 16, 0, 0);
    }
}

template<bool MASKED>
__device__ __forceinline__ void compute_tile(const bf16_t* bs,
                                             const bf16x8 (&afrag)[4][4],
                                             float (&ssum)[4][4],
                                             int n0, int lane, int l15) {
#pragma unroll
    for (int nf = 0; nf < 8; ++nf) {
        const bf16_t* bp = bs + nf * 2048 + lane * 8;
        bf16x8 b0 = *reinterpret_cast<const bf16x8*>(bp);
        bf16x8 b1 = *reinterpret_cast<const bf16x8*>(bp + 512);
        bf16x8 b2 = *reinterpret_cast<const bf16x8*>(bp + 1024);
        bf16x8 b3 = *reinterpret_cast<const bf16x8*>(bp + 1536);

        floatx4 acc[4];
#pragma unroll
        for (int mf = 0; mf < 4; ++mf) acc[mf] = (floatx4){0.f, 0.f, 0.f, 0.f};
#pragma unroll
        for (int mf = 0; mf < 4; ++mf)
            acc[mf] = __builtin_amdgcn_mfma_f32_16x16x32_bf16(afrag[mf][0], b0, acc[mf], 0, 0, 0);
#pragma unroll
        for (int mf = 0; mf < 4; ++mf)
            acc[mf] = __builtin_amdgcn_mfma_f32_16x16x32_bf16(afrag[mf][1], b1, acc[mf], 0, 0, 0);
#pragma unroll
        for (int mf = 0; mf < 4; ++mf)
            acc[mf] = __builtin_amdgcn_mfma_f32_16x16x32_bf16(afrag[mf][2], b2, acc[mf], 0, 0, 0);
#pragma unroll
        for (int mf = 0; mf < 4; ++mf)
            acc[mf] = __builtin_amdgcn_mfma_f32_16x16x32_bf16(afrag[mf][3], b3, acc[mf], 0, 0, 0);

        const bool ok = !MASKED || ((n0 + nf * 16 + l15) < VOCAB);
#pragma unroll
        for (int mf = 0; mf < 4; ++mf) {
#pragma unroll
            for (int r = 0; r < 4; ++r) {
                float e = EXP2(acc[mf][r]);
                ssum[mf][r] += ok ? e : 0.f;
            }
        }
    }
}

__launch_bounds__(256, 2)
__global__ void k_gemm(const bf16_t* __restrict__ A, const bf16_t* __restrict__ Wb,
                       float* __restrict__ sumexp) {
    __shared__ bf16_t Bs[2][32 * 512];   // 2 x 32 KiB double buffer
    const int tid  = threadIdx.x;
    const int lane = tid & 63;
    const int wv   = tid >> 6;     // 0..3
    const int l15  = lane & 15;
    const int q    = lane >> 4;    // 0..3
    const int m0   = blockIdx.x * BM;
    const int by   = blockIdx.y;   // 0..31

    // ---- Prologue: stage first tile; A-fragment preload overlaps its latency ----
    stage_tile(Wb, &Bs[0][0], by * BN, wv, l15, q);

    bf16x8 afrag[4][4];
#pragma unroll
    for (int mf = 0; mf < 4; ++mf) {
        const bf16_t* ap = A + (long)(m0 + wv * 64 + mf * 16 + l15) * DMODEL + q * 8;
#pragma unroll
        for (int ks = 0; ks < 4; ++ks)
            afrag[mf][ks] = *reinterpret_cast<const bf16x8*>(ap + ks * 32);
    }

    float ssum[4][4];
#pragma unroll
    for (int mf = 0; mf < 4; ++mf)
#pragma unroll
        for (int r = 0; r < 4; ++r) ssum[mf][r] = 0.f;

    asm volatile("s_waitcnt vmcnt(0)" ::: "memory");
    __builtin_amdgcn_s_barrier();
    __builtin_amdgcn_sched_barrier(0);

    // ---- Main loop: stage(next) || compute(cur); one vmcnt(0)+barrier per tile ----
    int cur = 0;
    for (int nt = by; nt < NTILES; nt += NSPLIT) {
        const int nnext = nt + NSPLIT;
        if (nnext < NTILES)
            stage_tile(Wb, &Bs[cur ^ 1][0], nnext * BN, wv, l15, q);

        const int n0 = nt * BN;
        const bf16_t* bs = &Bs[cur][0];
        if (n0 + BN <= VOCAB)
            compute_tile<false>(bs, afrag, ssum, n0, lane, l15);
        else
            compute_tile<true>(bs, afrag, ssum, n0, lane, l15);

        asm volatile("s_waitcnt vmcnt(0)" ::: "memory");
        __builtin_amdgcn_s_barrier();
        __builtin_amdgcn_sched_barrier(0);
        cur ^= 1;
    }

    // ---- Final reduce over 16 lanes + one atomic per row per block ----
    // C/D layout: col = l15, row = q*4 + reg.
#pragma unroll
    for (int mf = 0; mf < 4; ++mf) {
        float s0 = ssum[mf][0], s1 = ssum[mf][1], s2 = ssum[mf][2], s3 = ssum[mf][3];
#pragma unroll
        for (int off = 1; off < 16; off <<= 1) {
            s0 += __shfl_xor(s0, off, 64);
            s1 += __shfl_xor(s1, off, 64);
            s2 += __shfl_xor(s2, off, 64);
            s3 += __shfl_xor(s3, off, 64);
        }
        if (l15 == 0) {
            const int rbase = m0 + wv * 64 + mf * 16 + q * 4;
            atomicAdd(&sumexp[rbase + 0], s0);
            atomicAdd(&sumexp[rbase + 1], s1);
            atomicAdd(&sumexp[rbase + 2], s2);
            atomicAdd(&sumexp[rbase + 3], s3);
        }
    }
}

// ---------------------------------------------------------------------------
// Kernel 3: loss = mean_b( ln(sumexp[b]) - center_logit[b] ). One block.
// ---------------------------------------------------------------------------
__global__ void k_loss(const float* __restrict__ sumexp,
                       const float* __restrict__ center_logit,
                       float* __restrict__ out) {
    float acc = 0.f;
    for (int b = threadIdx.x; b < BATCH; b += 256)
        acc += logf(sumexp[b]) - center_logit[b];
#pragma unroll
    for (int off = 32; off >= 1; off >>= 1) acc += __shfl_xor(acc, off, 64);
    __shared__ float red[4];
    if ((threadIdx.x & 63) == 0) red[threadIdx.x >> 6] = acc;
    __syncthreads();
    if (threadIdx.x == 0)
        out[0] = (red[0] + red[1] + red[2] + red[3]) * (1.0f / BATCH);
}

// ---------------------------------------------------------------------------
extern "C" void kernel_launch(void* const* d_in, const int* in_sizes, int n_in,
                              void* d_out, int out_size, void* d_ws, size_t ws_size,
                              hipStream_t stream) {
    const int*   ctx    = (const int*)d_in[0];
    const int*   center = (const int*)d_in[1];
    const float* emb    = (const float*)d_in[2];
    const float* W      = (const float*)d_in[3];
    float*       out    = (float*)d_out;

    char* ws = (char*)d_ws;
    // layout: Wb (VPAD*128*2 = 12,877,824 B) | cbow (1,048,576 B)
    //         | center_logit (16,384 B) | sumexp (16,384 B)
    bf16_t* Wb           = (bf16_t*)ws;
    bf16_t* cbow         = (bf16_t*)(ws + 12877824);
    float*  center_logit = (float*)(ws + 13926400);
    float*  sumexp       = (float*)(ws + 13942784);

    k_prep<<<PREP_CBOW_BLOCKS + PREP_WCONV_BLOCKS, 256, 0, stream>>>(
        ctx, center, emb, W, cbow, Wb, center_logit, sumexp);
    dim3 g2(BATCH / BM, NSPLIT);
    k_gemm<<<g2, 256, 0, stream>>>(cbow, Wb, sumexp);
    k_loss<<<1, 256, 0, stream>>>(sumexp, center_logit, out);
}